// Round 2
// baseline (4117.910 us; speedup 1.0000x reference)
//
#include <hip/hip_runtime.h>

// Fully-fused BetaVAE encoder: one 512-thread block per image.
// R2: force register-resident accumulators (ext_vector), batch LDS reads
// before FMA streams (separate ds vs smem lgkm waits), scalar weights.
//
// LDS map (bytes):
//   [0      , 41616): xs  [6][102][34] u16/bf16 (padded x) -- later reused:
//        [0    ,25600): h2s [16][50][16]
//        [25600,30720): h3s [32][10][8]
//   [41616  , 56592): p1s [8][52][18]
//   [56592  , 60432): p2s [16][12][10]
//   [60432  , 61456): f   [256] float
#define SMEM_BYTES 61456

typedef float f32x8  __attribute__((ext_vector_type(8)));
typedef float f32x16 __attribute__((ext_vector_type(16)));

__device__ __forceinline__ float bf2f(unsigned short u) {
    union { unsigned int i; float f; } v; v.i = ((unsigned int)u) << 16; return v.f;
}
__device__ __forceinline__ unsigned short f2bf(float f) {
    union { float f; unsigned int i; } v; v.f = f;
    unsigned int r = v.i + 0x7FFF + ((v.i >> 16) & 1);   // RNE (no NaN in range)
    return (unsigned short)(r >> 16);
}
__device__ __forceinline__ float lrelu(float v) { return fmaxf(v, 0.01f * v); }
__device__ __forceinline__ void fma8(f32x8& a, const f32x8& w, float x) {
    #pragma unroll
    for (int o = 0; o < 8; o++) a[o] = __builtin_fmaf(w[o], x, a[o]);
}
__device__ __forceinline__ void fma16(f32x16& a, const f32x16& w, float x) {
    #pragma unroll
    for (int o = 0; o < 16; o++) a[o] = __builtin_fmaf(w[o], x, a[o]);
}

extern "C" __global__ void __launch_bounds__(512, 4)
vae_encoder_kernel(const float* __restrict__ x,
                   const float* __restrict__ w1,  const float* __restrict__ b1,
                   const float* __restrict__ w2,  const float* __restrict__ b2,
                   const float* __restrict__ w3,  const float* __restrict__ b3,
                   const float* __restrict__ wp1, const float* __restrict__ bp1,
                   const float* __restrict__ wp2, const float* __restrict__ bp2,
                   const float* __restrict__ wp3, const float* __restrict__ bp3,
                   const float* __restrict__ wmu, const float* __restrict__ bmu,
                   const float* __restrict__ wlv, const float* __restrict__ blv,
                   float* __restrict__ out)
{
    __shared__ __align__(16) unsigned char smem[SMEM_BYTES];
    unsigned short* xs  = (unsigned short*)(smem);            // [6][102][34]
    unsigned short* h2s = (unsigned short*)(smem);            // [16][50][16]
    unsigned short* h3s = (unsigned short*)(smem + 25600);    // [32][10][8]
    unsigned short* p1s = (unsigned short*)(smem + 41616);    // [8][52][18]
    unsigned short* p2s = (unsigned short*)(smem + 56592);    // [16][12][10]
    float*          fv  = (float*)(smem + 60432);             // [256]

    const int tid  = threadIdx.x;
    const int b    = blockIdx.x;
    const int lane = tid & 63;
    const int wave = tid >> 6;

    // ---- 0) zero LDS (padding borders must be 0) ----
    for (int i = tid; i < SMEM_BYTES / 16; i += 512)
        ((int4*)smem)[i] = int4{0, 0, 0, 0};
    __syncthreads();

    // ---- 1) x image -> xs (bf16, +1 halo pad) ----
    const float* xb = x + (size_t)b * 19200;
    for (int i = tid; i < 4800; i += 512) {
        float4 v = ((const float4*)xb)[i];
        int c   = i / 800;
        int rem = i - c * 800;
        int row = rem >> 3;
        int c4  = rem & 7;
        int base = c * 3468 + (row + 1) * 34 + (c4 * 4 + 1);
        xs[base + 0] = f2bf(v.x); xs[base + 1] = f2bf(v.y);
        xs[base + 2] = f2bf(v.z); xs[base + 3] = f2bf(v.w);
    }
    __syncthreads();

    // ---- 2) conv1(3x3 SAME,6->8)+lrelu fused with pool1(2x2/2) ----
    for (int pos = tid; pos < 800; pos += 512) {
        const int pr = pos >> 4, pc = pos & 15;
        f32x8 h00, h01, h10, h11;
        #pragma unroll
        for (int o = 0; o < 8; o++) { float bv = b1[o]; h00[o]=bv; h01[o]=bv; h10[o]=bv; h11[o]=bv; }
        #pragma unroll
        for (int c = 0; c < 6; c++) {
            // batch: 4x4 padded-x window covering all 4 conv outputs
            float xw[16];
            #pragma unroll
            for (int i = 0; i < 4; i++)
                #pragma unroll
                for (int j = 0; j < 4; j++)
                    xw[i * 4 + j] = bf2f(xs[c * 3468 + (2 * pr + i) * 34 + (2 * pc + j)]);
            #pragma unroll
            for (int dy = 0; dy < 3; dy++)
                #pragma unroll
                for (int dx = 0; dx < 3; dx++) {
                    f32x8 wv;
                    #pragma unroll
                    for (int o = 0; o < 8; o++) wv[o] = w1[o * 54 + c * 9 + dy * 3 + dx];
                    fma8(h00, wv, xw[dy * 4 + dx]);
                    fma8(h01, wv, xw[dy * 4 + dx + 1]);
                    fma8(h10, wv, xw[(dy + 1) * 4 + dx]);
                    fma8(h11, wv, xw[(dy + 1) * 4 + dx + 1]);
                }
        }
        f32x8 acc;
        #pragma unroll
        for (int o = 0; o < 8; o++) acc[o] = bp1[o];
        #pragma unroll
        for (int ic = 0; ic < 8; ic++) {
            float v00 = lrelu(h00[ic]), v01 = lrelu(h01[ic]);
            float v10 = lrelu(h10[ic]), v11 = lrelu(h11[ic]);
            #pragma unroll
            for (int o = 0; o < 8; o++) {
                acc[o] = __builtin_fmaf(wp1[(o * 8 + ic) * 4 + 0], v00, acc[o]);
                acc[o] = __builtin_fmaf(wp1[(o * 8 + ic) * 4 + 1], v01, acc[o]);
                acc[o] = __builtin_fmaf(wp1[(o * 8 + ic) * 4 + 2], v10, acc[o]);
                acc[o] = __builtin_fmaf(wp1[(o * 8 + ic) * 4 + 3], v11, acc[o]);
            }
        }
        #pragma unroll
        for (int o = 0; o < 8; o++)
            p1s[o * 936 + (pr + 1) * 18 + (pc + 1)] = f2bf(acc[o]);
    }
    __syncthreads();

    // ---- 3) conv2(3x3 SAME,8->16)+lrelu -> h2s (overwrites xs) ----
    for (int pos = tid; pos < 800; pos += 512) {
        const int r = pos >> 4, c = pos & 15;
        f32x16 acc;
        #pragma unroll
        for (int o = 0; o < 16; o++) acc[o] = b2[o];
        #pragma unroll
        for (int ic = 0; ic < 8; ic++) {
            float xw[9];
            #pragma unroll
            for (int dy = 0; dy < 3; dy++)
                #pragma unroll
                for (int dx = 0; dx < 3; dx++)
                    xw[dy * 3 + dx] = bf2f(p1s[ic * 936 + (r + dy) * 18 + (c + dx)]);
            #pragma unroll
            for (int dy = 0; dy < 3; dy++)
                #pragma unroll
                for (int dx = 0; dx < 3; dx++) {
                    f32x16 wv;
                    #pragma unroll
                    for (int o = 0; o < 16; o++) wv[o] = w2[o * 72 + ic * 9 + dy * 3 + dx];
                    fma16(acc, wv, xw[dy * 3 + dx]);
                }
        }
        #pragma unroll
        for (int o = 0; o < 16; o++)
            h2s[o * 800 + pos] = f2bf(lrelu(acc[o]));
    }
    __syncthreads();

    // ---- 4) pool2 (5x2 stride (5,2), 16->16) -> p2s ----
    {
        const int oc0 = __builtin_amdgcn_readfirstlane(wave);   // 0..7
        for (int pos = lane; pos < 80; pos += 64) {
            const int pr = pos >> 3, pc = pos & 7;
            float a0 = bp2[oc0], a1 = bp2[oc0 + 8];
            #pragma unroll
            for (int ic = 0; ic < 16; ic++) {
                float xv[10];
                #pragma unroll
                for (int kh = 0; kh < 5; kh++)
                    #pragma unroll
                    for (int kw = 0; kw < 2; kw++)
                        xv[kh * 2 + kw] = bf2f(h2s[ic * 800 + (5 * pr + kh) * 16 + (2 * pc + kw)]);
                #pragma unroll
                for (int k = 0; k < 10; k++) {
                    a0 = __builtin_fmaf(wp2[(oc0 * 16 + ic) * 10 + k],       xv[k], a0);
                    a1 = __builtin_fmaf(wp2[((oc0 + 8) * 16 + ic) * 10 + k], xv[k], a1);
                }
            }
            p2s[oc0 * 120 + (pr + 1) * 10 + (pc + 1)]       = f2bf(a0);
            p2s[(oc0 + 8) * 120 + (pr + 1) * 10 + (pc + 1)] = f2bf(a1);
        }
    }
    __syncthreads();

    // ---- 5) conv3(3x3 SAME,16->32)+lrelu -> h3s ----
    {
        const int pos = tid & 127;
        const int ocq = __builtin_amdgcn_readfirstlane(tid >> 7);   // 0..3
        if (pos < 80) {
            const int r = pos >> 3, c = pos & 7;
            f32x8 acc;
            #pragma unroll
            for (int o = 0; o < 8; o++) acc[o] = b3[ocq * 8 + o];
            #pragma unroll
            for (int ic = 0; ic < 16; ic++) {
                float xw[9];
                #pragma unroll
                for (int dy = 0; dy < 3; dy++)
                    #pragma unroll
                    for (int dx = 0; dx < 3; dx++)
                        xw[dy * 3 + dx] = bf2f(p2s[ic * 120 + (r + dy) * 10 + (c + dx)]);
                #pragma unroll
                for (int dy = 0; dy < 3; dy++)
                    #pragma unroll
                    for (int dx = 0; dx < 3; dx++) {
                        f32x8 wv;
                        #pragma unroll
                        for (int o = 0; o < 8; o++)
                            wv[o] = w3[(ocq * 8 + o) * 144 + ic * 9 + dy * 3 + dx];
                        fma8(acc, wv, xw[dy * 3 + dx]);
                    }
            }
            #pragma unroll
            for (int o = 0; o < 8; o++)
                h3s[(ocq * 8 + o) * 80 + pos] = f2bf(lrelu(acc[o]));
        }
    }
    __syncthreads();

    // ---- 6) pool3 (5x2 stride (5,2), 32->32) -> fv[256] ----
    {
        const int oc_g = __builtin_amdgcn_readfirstlane(wave);  // 0..7
        const int pos  = lane & 7;                              // 2x4 grid
        const int icg  = lane >> 3;                             // 8 groups of 4 ic
        const int pr = pos >> 2, pc = pos & 3;
        float xv[40];
        #pragma unroll
        for (int j = 0; j < 4; j++) {
            const int ic = icg * 4 + j;
            #pragma unroll
            for (int kh = 0; kh < 5; kh++)
                #pragma unroll
                for (int kw = 0; kw < 2; kw++)
                    xv[j * 10 + kh * 2 + kw] =
                        bf2f(h3s[ic * 80 + (5 * pr + kh) * 8 + (2 * pc + kw)]);
        }
        #pragma unroll
        for (int sub = 0; sub < 4; sub++) {
            const int oc = oc_g * 4 + sub;
            float partial = 0.f;
            #pragma unroll
            for (int j = 0; j < 4; j++)
                #pragma unroll
                for (int k = 0; k < 10; k++)
                    partial = __builtin_fmaf(wp3[(oc * 32 + icg * 4 + j) * 10 + k],
                                             xv[j * 10 + k], partial);
            partial += __shfl_xor(partial, 8);
            partial += __shfl_xor(partial, 16);
            partial += __shfl_xor(partial, 32);
            if (icg == 0) fv[oc * 8 + pos] = partial + bp3[oc];
        }
    }
    __syncthreads();

    // ---- 7) heads ----
    {
        const int j = __builtin_amdgcn_readfirstlane(wave);     // 0..6 used
        if (j < 7) {
            #pragma unroll
            for (int head = 0; head < 2; head++) {
                const float* W = head ? wlv : wmu;
                float s = 0.f;
                #pragma unroll
                for (int q = 0; q < 4; q++) {
                    int k = lane + 64 * q;
                    s = __builtin_fmaf(fv[k], W[j * 256 + k], s);
                }
                #pragma unroll
                for (int m = 1; m < 64; m <<= 1) s += __shfl_xor(s, m);
                if (lane == 0) {
                    float r = s + (head ? blv[j] : bmu[j]);
                    if (head) r = fminf(fmaxf(r, -5.f), 0.f);
                    out[head * 28672 + b * 7 + j] = r;
                }
            }
        }
    }
}

extern "C" void kernel_launch(void* const* d_in, const int* in_sizes, int n_in,
                              void* d_out, int out_size, void* d_ws, size_t ws_size,
                              hipStream_t stream) {
    const float* x   = (const float*)d_in[0];
    const float* w1  = (const float*)d_in[1];
    const float* b1  = (const float*)d_in[2];
    const float* w2  = (const float*)d_in[3];
    const float* b2  = (const float*)d_in[4];
    const float* w3  = (const float*)d_in[5];
    const float* b3  = (const float*)d_in[6];
    const float* wp1 = (const float*)d_in[7];
    const float* bp1 = (const float*)d_in[8];
    const float* wp2 = (const float*)d_in[9];
    const float* bp2 = (const float*)d_in[10];
    const float* wp3 = (const float*)d_in[11];
    const float* bp3 = (const float*)d_in[12];
    const float* wmu = (const float*)d_in[13];
    const float* bmu = (const float*)d_in[14];
    const float* wlv = (const float*)d_in[15];
    const float* blv = (const float*)d_in[16];
    float* out = (float*)d_out;

    hipLaunchKernelGGL(vae_encoder_kernel, dim3(4096), dim3(512), 0, stream,
                       x, w1, b1, w2, b2, w3, b3, wp1, bp1, wp2, bp2, wp3, bp3,
                       wmu, bmu, wlv, blv, out);
}

// Round 3
// 1969.127 us; speedup vs baseline: 2.0912x; 2.0912x over previous
//
#include <hip/hip_runtime.h>

// R3: fully-fused BetaVAE encoder, one 512-thread block per image.
// Weights staged per-stage into LDS (fp32, oc-innermost transpose) to kill
// LICM-hoisted global weight loads that spilled to scratch in R1/R2.
// Activations bf16 in LDS, fp32 accumulation, wave-uniform weight reads
// (ds_read_b128 broadcast).

#define NT 512

// ---- LDS byte offsets ----
// activations
#define O_XS    0        // [6][102][34] bf16 = 41616
#define O_H2S   0        // [16][800]    bf16 = 25600  (xs dead)
#define O_H3S   25600    // [32][80]     bf16 = 5120   -> 30720
#define O_P1S   41616    // [8][52][18]  bf16 = 14976  -> 56592
#define O_P2S   56592    // [16][12][10] bf16 = 3840   -> 60432
#define O_FV    60432    // [256] f32    = 1024        -> 61456
// per-stage weights (fp32), placed in regions dead at that stage
#define O_W1T   61456    // [54][8]   1728 -> 63184   (stage 2)
#define O_B1    63184    //   32 -> 63216
#define O_WP1T  63216    // [4][8][8] 1024 -> 64240
#define O_BP1   64240    //   32 -> 64272
#define O_W2T   25600    // [72][16]  4608 -> 30208   (stage 3)
#define O_B2    30208    //   64 -> 30272
#define O_WP2   41616    // [16][160] 10240 -> 51856  (stage 4)
#define O_BP2   51856    //   64 -> 51920
#define O_W3T   0        // [144][32] 18432 -> 18432  (stage 5)
#define O_B3    18432    //  128 -> 18560
#define O_WP3A  0        // oc 0..15, row stride 324: 20736       (stage 6)
#define O_BP3   20736    //  128 -> 20864
#define O_WP3B  30720    // oc 16..31: 20736 -> 51456
#define O_WMU   0        // [7][256] 7168            (stage 7)
#define O_WLV   7168     // 7168 -> 14336
#define O_BMU   14336    //   28
#define O_BLV   14368    //   28 -> 14396

#define SMEM_BYTES 64288

typedef float f32x8  __attribute__((ext_vector_type(8)));
typedef float f32x16 __attribute__((ext_vector_type(16)));

__device__ __forceinline__ float bf2f(unsigned short u) {
    union { unsigned int i; float f; } v; v.i = ((unsigned int)u) << 16; return v.f;
}
__device__ __forceinline__ float bflo(unsigned int u) {
    union { unsigned int i; float f; } v; v.i = u << 16; return v.f;
}
__device__ __forceinline__ float bfhi(unsigned int u) {
    union { unsigned int i; float f; } v; v.i = u & 0xffff0000u; return v.f;
}
__device__ __forceinline__ unsigned short f2bf(float f) {
    union { float f; unsigned int i; } v; v.f = f;
    unsigned int r = v.i + 0x7FFF + ((v.i >> 16) & 1);   // RNE
    return (unsigned short)(r >> 16);
}
__device__ __forceinline__ float lrelu(float v) { return fmaxf(v, 0.01f * v); }

__device__ __forceinline__ void fma8v(f32x8& a, const float4& wA, const float4& wB, float x) {
    a[0] = __builtin_fmaf(wA.x, x, a[0]); a[1] = __builtin_fmaf(wA.y, x, a[1]);
    a[2] = __builtin_fmaf(wA.z, x, a[2]); a[3] = __builtin_fmaf(wA.w, x, a[3]);
    a[4] = __builtin_fmaf(wB.x, x, a[4]); a[5] = __builtin_fmaf(wB.y, x, a[5]);
    a[6] = __builtin_fmaf(wB.z, x, a[6]); a[7] = __builtin_fmaf(wB.w, x, a[7]);
}
__device__ __forceinline__ void fma16v(f32x16& a, const float4& w0, const float4& w1,
                                       const float4& w2, const float4& w3, float x) {
    a[0]  = __builtin_fmaf(w0.x, x, a[0]);  a[1]  = __builtin_fmaf(w0.y, x, a[1]);
    a[2]  = __builtin_fmaf(w0.z, x, a[2]);  a[3]  = __builtin_fmaf(w0.w, x, a[3]);
    a[4]  = __builtin_fmaf(w1.x, x, a[4]);  a[5]  = __builtin_fmaf(w1.y, x, a[5]);
    a[6]  = __builtin_fmaf(w1.z, x, a[6]);  a[7]  = __builtin_fmaf(w1.w, x, a[7]);
    a[8]  = __builtin_fmaf(w2.x, x, a[8]);  a[9]  = __builtin_fmaf(w2.y, x, a[9]);
    a[10] = __builtin_fmaf(w2.z, x, a[10]); a[11] = __builtin_fmaf(w2.w, x, a[11]);
    a[12] = __builtin_fmaf(w3.x, x, a[12]); a[13] = __builtin_fmaf(w3.y, x, a[13]);
    a[14] = __builtin_fmaf(w3.z, x, a[14]); a[15] = __builtin_fmaf(w3.w, x, a[15]);
}

extern "C" __global__ void __launch_bounds__(512, 4)
vae_encoder_kernel(const float* __restrict__ x,
                   const float* __restrict__ w1,  const float* __restrict__ b1,
                   const float* __restrict__ w2,  const float* __restrict__ b2,
                   const float* __restrict__ w3,  const float* __restrict__ b3,
                   const float* __restrict__ wp1, const float* __restrict__ bp1,
                   const float* __restrict__ wp2, const float* __restrict__ bp2,
                   const float* __restrict__ wp3, const float* __restrict__ bp3,
                   const float* __restrict__ wmu, const float* __restrict__ bmu,
                   const float* __restrict__ wlv, const float* __restrict__ blv,
                   float* __restrict__ out)
{
    __shared__ __align__(16) unsigned char smem[SMEM_BYTES];
    unsigned short* xs  = (unsigned short*)(smem + O_XS);
    unsigned short* h2s = (unsigned short*)(smem + O_H2S);
    unsigned short* h3s = (unsigned short*)(smem + O_H3S);
    unsigned short* p1s = (unsigned short*)(smem + O_P1S);
    unsigned short* p2s = (unsigned short*)(smem + O_P2S);
    float*          fv  = (float*)(smem + O_FV);

    const int tid  = threadIdx.x;
    const int b    = blockIdx.x;
    const int lane = tid & 63;
    const int wave = tid >> 6;

    // ---- 0) zero activation LDS (halo borders must be 0) ----
    for (int i = tid; i < 3841; i += NT)           // 3841*16 = 61456
        ((int4*)smem)[i] = int4{0, 0, 0, 0};
    __syncthreads();

    // ---- 1) load x -> xs (bf16, +1 halo)  +  copy stage-2 weights ----
    {
        const float* xb = x + (size_t)b * 19200;
        for (int i = tid; i < 4800; i += NT) {
            float4 v = ((const float4*)xb)[i];
            int c   = i / 800;
            int rem = i - c * 800;
            int row = rem >> 3;
            int c4  = rem & 7;
            int base = c * 3468 + (row + 1) * 34 + (c4 * 4 + 1);
            xs[base + 0] = f2bf(v.x); xs[base + 1] = f2bf(v.y);
            xs[base + 2] = f2bf(v.z); xs[base + 3] = f2bf(v.w);
        }
        float* w1t  = (float*)(smem + O_W1T);
        float* b1s  = (float*)(smem + O_B1);
        float* wp1t = (float*)(smem + O_WP1T);
        float* bp1s = (float*)(smem + O_BP1);
        for (int i = tid; i < 432; i += NT) {      // w1t[r][o] = w1[o][r]
            int o = i & 7, r = i >> 3;
            w1t[i] = w1[o * 54 + r];
        }
        for (int i = tid; i < 256; i += NT) {      // wp1t[k][ic][o] = wp1[o][ic][k]
            int o = i & 7, ic = (i >> 3) & 7, k = i >> 6;
            wp1t[i] = wp1[(o * 8 + ic) * 4 + k];
        }
        if (tid < 8)  b1s[tid]  = b1[tid];
        if (tid < 8)  bp1s[tid] = bp1[tid];
    }
    __syncthreads();

    // ---- 2) conv1(3x3,6->8)+lrelu fused with pool1(2x2/2,8->8) -> p1s ----
    {
        const float* w1s  = (const float*)(smem + O_W1T);
        const float* b1s  = (const float*)(smem + O_B1);
        const float* wp1s = (const float*)(smem + O_WP1T);
        const float* bp1s = (const float*)(smem + O_BP1);
        #pragma unroll 1
        for (int pos = tid; pos < 800; pos += NT) {
            const int pr = pos >> 4, pc = pos & 15;
            const int row0 = 2 * pr, col0 = 2 * pc;   // padded coords
            f32x8 h00, h01, h10, h11;
            {
                float4 bA = *(const float4*)&b1s[0];
                float4 bB = *(const float4*)&b1s[4];
                h00[0]=bA.x; h00[1]=bA.y; h00[2]=bA.z; h00[3]=bA.w;
                h00[4]=bB.x; h00[5]=bB.y; h00[6]=bB.z; h00[7]=bB.w;
                h01 = h00; h10 = h00; h11 = h00;
            }
            #pragma unroll 1
            for (int c = 0; c < 6; c++) {
                float xw[16];
                #pragma unroll
                for (int i = 0; i < 4; i++) {
                    const unsigned int* rp =
                        (const unsigned int*)&xs[c * 3468 + (row0 + i) * 34 + col0];
                    unsigned int u0 = rp[0], u1 = rp[1];
                    xw[i*4+0] = bflo(u0); xw[i*4+1] = bfhi(u0);
                    xw[i*4+2] = bflo(u1); xw[i*4+3] = bfhi(u1);
                }
                #pragma unroll
                for (int dy = 0; dy < 3; dy++)
                    #pragma unroll
                    for (int dx = 0; dx < 3; dx++) {
                        const float* wg = &w1s[(c * 9 + dy * 3 + dx) * 8];
                        float4 wA = *(const float4*)&wg[0];
                        float4 wB = *(const float4*)&wg[4];
                        fma8v(h00, wA, wB, xw[dy*4+dx]);
                        fma8v(h01, wA, wB, xw[dy*4+dx+1]);
                        fma8v(h10, wA, wB, xw[(dy+1)*4+dx]);
                        fma8v(h11, wA, wB, xw[(dy+1)*4+dx+1]);
                    }
            }
            f32x8 acc;
            {
                float4 bA = *(const float4*)&bp1s[0];
                float4 bB = *(const float4*)&bp1s[4];
                acc[0]=bA.x; acc[1]=bA.y; acc[2]=bA.z; acc[3]=bA.w;
                acc[4]=bB.x; acc[5]=bB.y; acc[6]=bB.z; acc[7]=bB.w;
            }
            #pragma unroll
            for (int ic = 0; ic < 8; ic++) {
                float v0 = lrelu(h00[ic]); float v1 = lrelu(h01[ic]);
                float v2 = lrelu(h10[ic]); float v3 = lrelu(h11[ic]);
                const float* g0 = &wp1s[(0 * 8 + ic) * 8];
                const float* g1 = &wp1s[(1 * 8 + ic) * 8];
                const float* g2 = &wp1s[(2 * 8 + ic) * 8];
                const float* g3 = &wp1s[(3 * 8 + ic) * 8];
                fma8v(acc, *(const float4*)&g0[0], *(const float4*)&g0[4], v0);
                fma8v(acc, *(const float4*)&g1[0], *(const float4*)&g1[4], v1);
                fma8v(acc, *(const float4*)&g2[0], *(const float4*)&g2[4], v2);
                fma8v(acc, *(const float4*)&g3[0], *(const float4*)&g3[4], v3);
            }
            #pragma unroll
            for (int o = 0; o < 8; o++)
                p1s[o * 936 + (pr + 1) * 18 + (pc + 1)] = f2bf(acc[o]);
        }
    }
    __syncthreads();

    // ---- copy stage-3 weights (w2 transposed) ----
    {
        float* w2t = (float*)(smem + O_W2T);
        float* b2s = (float*)(smem + O_B2);
        for (int i = tid; i < 1152; i += NT) {     // w2t[r][o] = w2[o][r]
            int o = i & 15, r = i >> 4;
            w2t[i] = w2[o * 72 + r];
        }
        if (tid < 16) b2s[tid] = b2[tid];
    }
    __syncthreads();

    // ---- 3) conv2(3x3,8->16)+lrelu -> h2s ----
    {
        const float* w2s = (const float*)(smem + O_W2T);
        const float* b2s = (const float*)(smem + O_B2);
        #pragma unroll 1
        for (int pos = tid; pos < 800; pos += NT) {
            const int r = pos >> 4, c = pos & 15;
            f32x16 acc;
            {
                float4 b0 = *(const float4*)&b2s[0];
                float4 b1v = *(const float4*)&b2s[4];
                float4 b2v = *(const float4*)&b2s[8];
                float4 b3v = *(const float4*)&b2s[12];
                acc[0]=b0.x;  acc[1]=b0.y;  acc[2]=b0.z;  acc[3]=b0.w;
                acc[4]=b1v.x; acc[5]=b1v.y; acc[6]=b1v.z; acc[7]=b1v.w;
                acc[8]=b2v.x; acc[9]=b2v.y; acc[10]=b2v.z; acc[11]=b2v.w;
                acc[12]=b3v.x; acc[13]=b3v.y; acc[14]=b3v.z; acc[15]=b3v.w;
            }
            #pragma unroll 1
            for (int ic = 0; ic < 8; ic++) {
                float xw[9];
                #pragma unroll
                for (int dy = 0; dy < 3; dy++) {
                    int base = ic * 936 + (r + dy) * 18 + c;
                    xw[dy*3+0] = bf2f(p1s[base + 0]);
                    xw[dy*3+1] = bf2f(p1s[base + 1]);
                    xw[dy*3+2] = bf2f(p1s[base + 2]);
                }
                #pragma unroll
                for (int k = 0; k < 9; k++) {
                    const float* wg = &w2s[(ic * 9 + k) * 16];
                    fma16v(acc, *(const float4*)&wg[0], *(const float4*)&wg[4],
                           *(const float4*)&wg[8], *(const float4*)&wg[12], xw[k]);
                }
            }
            #pragma unroll
            for (int o = 0; o < 16; o++)
                h2s[o * 800 + pos] = f2bf(lrelu(acc[o]));
        }
    }
    __syncthreads();

    // ---- copy stage-4 weights (wp2 plain) ----
    {
        float* wp2s = (float*)(smem + O_WP2);
        float* bp2s = (float*)(smem + O_BP2);
        for (int i = tid; i < 2560; i += NT) wp2s[i] = wp2[i];
        if (tid < 16) bp2s[tid] = bp2[tid];
    }
    __syncthreads();

    // ---- 4) pool2 (5x2 / (5,2), 16->16) -> p2s ----
    {
        const float* wp2s = (const float*)(smem + O_WP2);
        const float* bp2s = (const float*)(smem + O_BP2);
        const int oc0 = wave;                       // 0..7, handles oc0 & oc0+8
        #pragma unroll 1
        for (int pos = lane; pos < 80; pos += 64) {
            const int pr = pos >> 3, pc = pos & 7;
            float a0 = bp2s[oc0], a1 = bp2s[oc0 + 8];
            #pragma unroll 1
            for (int ic = 0; ic < 16; ic++) {
                float xv[10];
                #pragma unroll
                for (int kh = 0; kh < 5; kh++) {
                    unsigned int u = *(const unsigned int*)
                        &h2s[ic * 800 + (5 * pr + kh) * 16 + 2 * pc];
                    xv[kh*2+0] = bflo(u); xv[kh*2+1] = bfhi(u);
                }
                const float* wr0 = &wp2s[oc0 * 160 + ic * 10];
                const float* wr1 = &wp2s[(oc0 + 8) * 160 + ic * 10];
                #pragma unroll
                for (int k = 0; k < 10; k++) {
                    a0 = __builtin_fmaf(wr0[k], xv[k], a0);
                    a1 = __builtin_fmaf(wr1[k], xv[k], a1);
                }
            }
            p2s[oc0 * 120 + (pr + 1) * 10 + (pc + 1)]       = f2bf(a0);
            p2s[(oc0 + 8) * 120 + (pr + 1) * 10 + (pc + 1)] = f2bf(a1);
        }
    }
    __syncthreads();

    // ---- copy stage-5 weights (w3 transposed) ----
    {
        float* w3t = (float*)(smem + O_W3T);
        float* b3s = (float*)(smem + O_B3);
        for (int i = tid; i < 4608; i += NT) {     // w3t[r][o] = w3[o][r]
            int o = i & 31, r = i >> 5;
            w3t[i] = w3[o * 144 + r];
        }
        if (tid < 32) b3s[tid] = b3[tid];
    }
    __syncthreads();

    // ---- 5) conv3(3x3,16->32)+lrelu -> h3s ----
    {
        const float* w3s = (const float*)(smem + O_W3T);
        const float* b3s = (const float*)(smem + O_B3);
        const int ocg = wave;                       // 4 oc per wave
        #pragma unroll 1
        for (int pos = lane; pos < 80; pos += 64) {
            const int r = pos >> 3, cc = pos & 7;
            float4 bv = *(const float4*)&b3s[ocg * 4];
            float a0 = bv.x, a1 = bv.y, a2 = bv.z, a3 = bv.w;
            #pragma unroll 1
            for (int ic = 0; ic < 16; ic++) {
                float xw[9];
                #pragma unroll
                for (int dy = 0; dy < 3; dy++) {
                    int base = ic * 120 + (r + dy) * 10 + cc;
                    xw[dy*3+0] = bf2f(p2s[base + 0]);
                    xw[dy*3+1] = bf2f(p2s[base + 1]);
                    xw[dy*3+2] = bf2f(p2s[base + 2]);
                }
                #pragma unroll
                for (int k = 0; k < 9; k++) {
                    float4 w = *(const float4*)&w3s[(ic * 9 + k) * 32 + ocg * 4];
                    a0 = __builtin_fmaf(w.x, xw[k], a0);
                    a1 = __builtin_fmaf(w.y, xw[k], a1);
                    a2 = __builtin_fmaf(w.z, xw[k], a2);
                    a3 = __builtin_fmaf(w.w, xw[k], a3);
                }
            }
            h3s[(ocg*4+0)*80 + pos] = f2bf(lrelu(a0));
            h3s[(ocg*4+1)*80 + pos] = f2bf(lrelu(a1));
            h3s[(ocg*4+2)*80 + pos] = f2bf(lrelu(a2));
            h3s[(ocg*4+3)*80 + pos] = f2bf(lrelu(a3));
        }
    }
    __syncthreads();

    // ---- copy stage-6 weights (wp3, row stride 324 to spread banks) ----
    {
        float* wA = (float*)(smem + O_WP3A);
        float* wB = (float*)(smem + O_WP3B);
        float* bp3s = (float*)(smem + O_BP3);
        for (int oc = wave; oc < 32; oc += 8) {
            float* dst = (oc < 16) ? (wA + oc * 324) : (wB + (oc - 16) * 324);
            const float* src = wp3 + oc * 320;
            for (int j = lane; j < 320; j += 64) dst[j] = src[j];
        }
        if (tid < 32) bp3s[tid] = bp3[tid];
    }
    __syncthreads();

    // ---- 6) pool3 (5x2 / (5,2), 32->32) -> fv[256] ----
    {
        const float* bp3s = (const float*)(smem + O_BP3);
        if (tid < 256) {
            const int oc = tid >> 3, pos = tid & 7;
            const int pr = pos >> 2, pc = pos & 3;
            const float* wrow = (oc < 16)
                ? (const float*)(smem + O_WP3A) + oc * 324
                : (const float*)(smem + O_WP3B) + (oc - 16) * 324;
            float a = bp3s[oc];
            #pragma unroll 1
            for (int ic = 0; ic < 32; ic++) {
                float xv[10];
                #pragma unroll
                for (int kh = 0; kh < 5; kh++) {
                    unsigned int u = *(const unsigned int*)
                        &h3s[ic * 80 + (5 * pr + kh) * 8 + 2 * pc];
                    xv[kh*2+0] = bflo(u); xv[kh*2+1] = bfhi(u);
                }
                #pragma unroll
                for (int k = 0; k < 10; k++)
                    a = __builtin_fmaf(wrow[ic * 10 + k], xv[k], a);
            }
            fv[oc * 8 + pos] = a;                   // flatten [32][2][4]
        }
    }
    __syncthreads();

    // ---- copy stage-7 weights ----
    {
        float* wmus = (float*)(smem + O_WMU);
        float* wlvs = (float*)(smem + O_WLV);
        float* bmus = (float*)(smem + O_BMU);
        float* blvs = (float*)(smem + O_BLV);
        for (int i = tid; i < 1792; i += NT) wmus[i] = wmu[i];
        for (int i = tid; i < 1792; i += NT) wlvs[i] = wlv[i];
        if (tid < 7) bmus[tid] = bmu[tid];
        if (tid < 7) blvs[tid] = blv[tid];
    }
    __syncthreads();

    // ---- 7) heads ----
    {
        const float* wmus = (const float*)(smem + O_WMU);
        const float* wlvs = (const float*)(smem + O_WLV);
        const float* bmus = (const float*)(smem + O_BMU);
        const float* blvs = (const float*)(smem + O_BLV);
        if (wave < 7) {
            const int j = wave;
            #pragma unroll
            for (int head = 0; head < 2; head++) {
                const float* W = head ? wlvs : wmus;
                float s = 0.f;
                #pragma unroll
                for (int q = 0; q < 4; q++) {
                    int k = lane + 64 * q;
                    s = __builtin_fmaf(fv[k], W[j * 256 + k], s);
                }
                #pragma unroll
                for (int m = 1; m < 64; m <<= 1) s += __shfl_xor(s, m);
                if (lane == 0) {
                    float r = s + (head ? blvs[j] : bmus[j]);
                    if (head) r = fminf(fmaxf(r, -5.f), 0.f);
                    out[head * 28672 + b * 7 + j] = r;
                }
            }
        }
    }
}

extern "C" void kernel_launch(void* const* d_in, const int* in_sizes, int n_in,
                              void* d_out, int out_size, void* d_ws, size_t ws_size,
                              hipStream_t stream) {
    const float* x   = (const float*)d_in[0];
    const float* w1  = (const float*)d_in[1];
    const float* b1  = (const float*)d_in[2];
    const float* w2  = (const float*)d_in[3];
    const float* b2  = (const float*)d_in[4];
    const float* w3  = (const float*)d_in[5];
    const float* b3  = (const float*)d_in[6];
    const float* wp1 = (const float*)d_in[7];
    const float* bp1 = (const float*)d_in[8];
    const float* wp2 = (const float*)d_in[9];
    const float* bp2 = (const float*)d_in[10];
    const float* wp3 = (const float*)d_in[11];
    const float* bp3 = (const float*)d_in[12];
    const float* wmu = (const float*)d_in[13];
    const float* bmu = (const float*)d_in[14];
    const float* wlv = (const float*)d_in[15];
    const float* blv = (const float*)d_in[16];
    float* out = (float*)d_out;

    hipLaunchKernelGGL(vae_encoder_kernel, dim3(4096), dim3(512), 0, stream,
                       x, w1, b1, w2, b2, w3, b3, wp1, bp1, wp2, bp2, wp3, bp3,
                       wmu, bmu, wlv, blv, out);
}